// Round 1
// baseline (774.366 us; speedup 1.0000x reference)
//
#include <hip/hip_runtime.h>
#include <math.h>

typedef unsigned int   uint32;
typedef unsigned short ushort16;
typedef __attribute__((ext_vector_type(8))) short  short8;   // 8 bf16 (MFMA A/B frag)
typedef __attribute__((ext_vector_type(4))) float  floatx4;  // MFMA C/D frag

// Problem dims
#define Bb   512
#define QLn  128
#define ALn  512
#define En   300
#define Fn   400
#define OW   416      // packed output width: 400 real + 16 zero (832 B = 13*64)
#define EPAD 320      // e padded 300 -> 320 per shift; K_total = 3*320 = 960
#define NV   50001

typedef const __attribute__((address_space(1))) unsigned int guint_t;
typedef __attribute__((address_space(3))) unsigned int luint_t;
#define GLDS16(g, l) __builtin_amdgcn_global_load_lds((guint_t*)(g), (luint_t*)(l), 16, 0, 0)

static __device__ __forceinline__ float bf_lo(uint32 u) { return __uint_as_float(u << 16); }
static __device__ __forceinline__ float bf_hi(uint32 u) { return __uint_as_float(u & 0xffff0000u); }
static __device__ __forceinline__ ushort16 f2bf(float f) {
    uint32 u = __float_as_uint(f);
    uint32 r = (u + 0x7fffu + ((u >> 16) & 1u)) >> 16;   // RNE
    return (ushort16)r;
}
static __device__ __forceinline__ uint32 pack2(float a, float b) {
    return (uint32)f2bf(a) | ((uint32)f2bf(b) << 16);
}

// ---------------------------------------------------------------------------
// embcvt: embbf[v][0..320) = bf16(emb[v][0..300)), e>=300 zero.
// ---------------------------------------------------------------------------
__global__ __launch_bounds__(128) void embcvt_kernel(
        const float* __restrict__ emb, char* __restrict__ embbf)
{
    const int r = blockIdx.x, j = threadIdx.x;
    const float* er = emb + (size_t)r * En;
    uint32* orow = (uint32*)(embbf + (size_t)r * 640);
    for (int d = j; d < 160; d += 128) {
        uint32 v = 0;
        if (d < 150) {
            float2 f2v = *(const float2*)(er + 2 * d);
            v = pack2(f2v.x, f2v.y);
        }
        orow[d] = v;
    }
}

// ---------------------------------------------------------------------------
// prep_wt: Wt2[f][p] = W[f][e*3+kk] (p = kk*320+e), bf16, zero pad; bias2.
// ---------------------------------------------------------------------------
__global__ __launch_bounds__(256) void prep_wt(
        const float* __restrict__ W, const float* __restrict__ cb,
        ushort16* __restrict__ Wt2, float* __restrict__ bias2)
{
    const int f = blockIdx.x, t = threadIdx.x;
    for (int p2 = t; p2 < 480; p2 += 256) {
        int p = 2 * p2;
        float v0 = 0.f, v1 = 0.f;
        if (f < Fn) {
            int kk = p / EPAD, e = p - kk * EPAD;
            if (e < En)     v0 = W[(size_t)f * 900 + e * 3 + kk];
            if (e + 1 < En) v1 = W[(size_t)f * 900 + (e + 1) * 3 + kk];
        }
        *(uint32*)&Wt2[(size_t)f * 960 + p] = pack2(v0, v1);
    }
    if (t == 0) bias2[f] = (f < Fn) ? cb[f] : 0.f;
}

// ---------------------------------------------------------------------------
// prep_wp: Wp2[g][p] = sum_f U[f][g]*W[f][p900], fp32 accum, bf16 store.
// grid (30 p-chunks of 32, 4 g-chunks of 128). W chunk staged in LDS.
// ---------------------------------------------------------------------------
__global__ __launch_bounds__(256) void prep_wp(
        const float* __restrict__ W, const float* __restrict__ U,
        ushort16* __restrict__ Wp2)
{
    __shared__ float Wl[400 * 32];   // 51.2 KB
    const int t = threadIdx.x;
    const int pc = blockIdx.x, gc = blockIdx.y;
    const int kk = (pc * 32) / EPAD, e0 = pc * 32 - kk * EPAD;

    for (int i = t; i < 400 * 32; i += 256) {
        int f = i >> 5, j = i & 31, e = e0 + j;
        Wl[i] = (e < En) ? W[(size_t)f * 900 + e * 3 + kk] : 0.f;
    }
    __syncthreads();

    const int g = gc * 128 + (t >> 1);
    const int jh = (t & 1) * 16;
    float acc[16];
#pragma unroll
    for (int k = 0; k < 16; ++k) acc[k] = 0.f;

    for (int f = 0; f < Fn; ++f) {
        float uf = 0.f;
        if (g < Fn) uf = U[(size_t)f * Fn + g];
        const float* wl = Wl + f * 32 + jh;
#pragma unroll
        for (int k = 0; k < 16; ++k) acc[k] = fmaf(uf, wl[k], acc[k]);
    }
    ushort16* orow = Wp2 + (size_t)g * 960 + pc * 32 + jh;
#pragma unroll
    for (int k = 0; k < 16; k += 2)
        *(uint32*)&orow[k] = pack2(acc[k], acc[k + 1]);
}

// prep_bp: bp2[g] = sum_f U[f][g]*cb[f] (g<512, zero beyond 400)
__global__ __launch_bounds__(256) void prep_bp(
        const float* __restrict__ cb, const float* __restrict__ U,
        float* __restrict__ bp2)
{
    __shared__ float cbl[Fn];
    const int t = threadIdx.x;
    for (int f = t; f < Fn; f += 256) cbl[f] = cb[f];
    __syncthreads();
#pragma unroll
    for (int h = 0; h < 2; ++h) {
        int g = t + h * 256;
        float s = 0.f;
        if (g < Fn)
            for (int f = 0; f < Fn; ++f) s += cbl[f] * U[(size_t)f * Fn + g];
        bp2[g] = s;
    }
}

// ---------------------------------------------------------------------------
// conv tile body (templated on NF = n-frags per wave-col).
// NF=4: 128-col tile. NF=5: 144-col tile (cols col0..col0+144), wc0/wc1
// overlap 16 cols; wc0 stores frags 0..3, wc1 stores 0..4 + zero-pad 400..416.
// A rows gathered from embbf[tok] via per-lane GLDS; XOR swizzle by source-
// chunk permutation (16-row-aligned groups keep the slot invariant).
//
// Double-buffered 2-phase pipeline (T3 minimum form): issue next-step
// global_load_lds into buf^1 BEFORE ds_read+MFMA of buf, single barrier
// per step (the __syncthreads' vmcnt(0) drain lands the next buffer).
// LDS: As = 2 x 8192, Bs = 2 x 9216.
// ---------------------------------------------------------------------------
template<int NF>
static __device__ __forceinline__ void conv_tile_g(
        const int* __restrict__ tokrow, int l0, int L,
        const char* __restrict__ embbf,
        const char* __restrict__ WB,     // weight base already offset to col0
        const float* __restrict__ biasv, int col0,
        ushort16* __restrict__ ob,       // out row base, row stride OW
        char* As, char* Bs)
{
    const int t = threadIdx.x, lane = t & 63, w = t >> 6;
    const int wr = w >> 1, wc = w & 1;
    const int fm = lane & 15;
    const int cg = ((lane & 3) - ((lane >> 3) & 3)) & 3;
    const int srow = w * 16 + (lane >> 2);
    const int chunkOff = (((lane >> 4) + (fm >> 1)) & 3) * 16;

    const char* srcA[3][2];
#pragma unroll
    for (int kk = 0; kk < 3; ++kk)
#pragma unroll
        for (int i = 0; i < 2; ++i) {
            const int pos = l0 + srow + i * 64 - 1 + kk;
            const int tok = (pos >= 0 && pos < L) ? tokrow[pos] : 0;
            srcA[kk][i] = embbf + (size_t)tok * 640 + cg * 16;
        }
    const char* srcB0 = WB + (size_t)srow * 1920 + cg * 16;
    const char* srcB8 = WB + (size_t)(128 + (lane >> 2)) * 1920 + cg * 16;
    char* AsW = As + w * 1024;
    char* BsW = Bs + w * 1024;

    floatx4 acc[4][NF];
    const floatx4 zz = {0.f, 0.f, 0.f, 0.f};
#pragma unroll
    for (int m = 0; m < 4; ++m)
#pragma unroll
        for (int n = 0; n < NF; ++n) acc[m][n] = zz;

#define CSTAGE(kkc, ko, buf) do {                                             \
        const int _ko = (ko); const int _ao = (buf) * 8192;                   \
        const int _bo = (buf) * 9216;                                         \
        GLDS16(srcA[kkc][0] + _ko, AsW + _ao);                                \
        GLDS16(srcA[kkc][1] + _ko, AsW + _ao + 4096);                         \
        GLDS16(srcB0 + (kkc) * 640 + _ko, BsW + _bo);                         \
        GLDS16(srcB0 + 122880 + (kkc) * 640 + _ko, BsW + _bo + 4096);         \
        if (NF == 5 && w == 0)                                                \
            GLDS16(srcB8 + (kkc) * 640 + _ko, Bs + _bo + 8192);               \
    } while (0)

    int cur = 0;
    CSTAGE(0, 0, 0);
    __syncthreads();

#pragma unroll
    for (int kk = 0; kk < 3; ++kk) {
        const int kn = (kk < 2) ? kk + 1 : 0;   // folds to const after unroll
        for (int ks = 0; ks < 10; ++ks) {
            const int nxt = cur ^ 1;
            if (ks < 9)      CSTAGE(kk, (ks + 1) * 64, nxt);
            else if (kk < 2) CSTAGE(kn, 0, nxt);

            short8 af[4], bfv[NF];
            const char* Ac = As + cur * 8192;
            const char* Bc = Bs + cur * 9216;
#pragma unroll
            for (int m = 0; m < 4; ++m)
                af[m] = *(const short8*)(Ac + (wr * 64 + m * 16 + fm) * 64 + chunkOff);
#pragma unroll
            for (int n = 0; n < NF; ++n)
                bfv[n] = *(const short8*)(Bc + (wc * 64 + n * 16 + fm) * 64 + chunkOff);
            __builtin_amdgcn_s_setprio(1);
#pragma unroll
            for (int m = 0; m < 4; ++m)
#pragma unroll
                for (int n = 0; n < NF; ++n)
                    acc[m][n] = __builtin_amdgcn_mfma_f32_16x16x32_bf16(
                        af[m], bfv[n], acc[m][n], 0, 0, 0);
            __builtin_amdgcn_s_setprio(0);
            __syncthreads();
            cur = nxt;
        }
    }
#undef CSTAGE

    float bn[NF];
#pragma unroll
    for (int n = 0; n < NF; ++n) bn[n] = biasv[col0 + wc * 64 + n * 16 + fm];
    const int nStore = (NF == 5 && wc == 0) ? 4 : NF;
#pragma unroll
    for (int m = 0; m < 4; ++m) {
        const int row = wr * 64 + m * 16 + ((lane >> 4) * 4);
#pragma unroll
        for (int n = 0; n < NF; ++n) {
            if (n >= nStore) break;
            const int col = col0 + wc * 64 + n * 16 + fm;
#pragma unroll
            for (int r = 0; r < 4; ++r)
                ob[(size_t)(row + r) * OW + col] = f2bf(acc[m][n][r] + bn[n]);
        }
        if (NF == 5 && wc == 1) {
#pragma unroll
            for (int r = 0; r < 4; ++r)
                ob[(size_t)(row + r) * OW + 400 + fm] = (ushort16)0;
        }
    }
}

// Merged conv dispatch. Region 1 (bx < blocksA): A-conv, tiles T=b*4+mt, 3 z.
// Region 2: Q-convs, tiles T=b, 6 (z,wsel) variants. XCD-affine tile placement.
__global__ __launch_bounds__(256) void conv_all(
        const int* __restrict__ question, const int* __restrict__ answer,
        const char* __restrict__ embbf,
        const char* __restrict__ Wt2, const char* __restrict__ Wp2,
        const float* __restrict__ bias2, const float* __restrict__ bp2,
        ushort16* __restrict__ qb, ushort16* __restrict__ qpb,
        ushort16* __restrict__ ab, int nb, int blocksA)
{
    __shared__ __align__(16) char As[16384];   // 2 x 8192 (dbuf)
    __shared__ __align__(16) char Bs[18432];   // 2 x 9216 (dbuf)
    int bx = blockIdx.x;
    if (bx < blocksA) {
        const int xcd = bx & 7, rest = bx >> 3;
        const int z = rest % 3, g = rest / 3;
        const int T = g * 8 + xcd;
        if (T >= nb * 4) return;
        const int b = T >> 2, mt = T & 3;
        ushort16* ob = ab + ((size_t)b * ALn + (size_t)mt * 128) * OW;
        const int* tr = answer + (size_t)b * ALn;
        if (z == 2)
            conv_tile_g<5>(tr, mt * 128, ALn, embbf, Wt2 + (size_t)256 * 1920,
                           bias2, 256, ob, As, Bs);
        else
            conv_tile_g<4>(tr, mt * 128, ALn, embbf, Wt2 + (size_t)z * 245760,
                           bias2, z * 128, ob, As, Bs);
    } else {
        bx -= blocksA;
        const int xcd = bx & 7, rest = bx >> 3;
        const int z6 = rest % 6, g = rest / 6;
        const int T = g * 8 + xcd;
        if (T >= nb) return;
        const int zf = z6 >> 1, ws = z6 & 1;
        const char*  Wsel = ws ? Wp2 : Wt2;
        const float* bsel = ws ? bp2 : bias2;
        ushort16*    ob   = (ws ? qpb : qb) + (size_t)T * QLn * OW;
        const int* tr = question + (size_t)T * QLn;
        if (zf == 2)
            conv_tile_g<5>(tr, 0, QLn, embbf, Wsel + (size_t)256 * 1920,
                           bsel, 256, ob, As, Bs);
        else
            conv_tile_g<4>(tr, 0, QLn, embbf, Wsel + (size_t)zf * 245760,
                           bsel, zf * 128, ob, As, Bs);
    }
}

// ---------------------------------------------------------------------------
// fused_g: block (b, a-chunk c). Gpre = Q' A^T (K=416, cols 400..416 zeros).
// Double-buffered 2-phase pipeline, single barrier per K-step.
// ---------------------------------------------------------------------------
__global__ __launch_bounds__(256) void fused_g(
        const ushort16* __restrict__ Qp,   // [nb][128][416]
        const ushort16* __restrict__ Av,   // [nb][512][416]
        float* __restrict__ rowPart,       // [nb][4][128]
        float* __restrict__ colMg,         // [nb][512]
        int nb)
{
    __shared__ __align__(16) char Qs[16384];    // 2 x 8192 (dbuf)
    __shared__ __align__(16) char Asl[16384];   // 2 x 8192 (dbuf)
    __shared__ float rowM2[128][2];
    __shared__ float colM2[128][2];

    const int t = threadIdx.x, lane = t & 63, w = t >> 6;
    const int bx = blockIdx.x;
    const int xcd = bx & 7, rest = bx >> 3;
    const int c = rest & 3, g = rest >> 2;
    const int T = g * 8 + xcd;
    if (T >= nb) return;
    const int b = T;
    const int wr = w >> 1, wc = w & 1;
    const int fm = lane & 15;
    const int cg = ((lane & 3) - ((lane >> 3) & 3)) & 3;
    const int srow = w * 16 + (lane >> 2);
    const int chunkOff = (((lane >> 4) + (fm >> 1)) & 3) * 16;

    const char* Qpb = (const char*)Qp + (size_t)b * 106496;
    const char* Ab  = (const char*)Av + (size_t)b * 425984 + (size_t)c * 106496;
    const char* srcQ = Qpb + (size_t)srow * 832 + cg * 16;
    const char* srcA = Ab  + (size_t)srow * 832 + cg * 16;
    char* QsW = Qs + w * 1024;
    char* AsW = Asl + w * 1024;

    floatx4 acc[4][4];
    const floatx4 zz = {0.f, 0.f, 0.f, 0.f};
#pragma unroll
    for (int m = 0; m < 4; ++m)
#pragma unroll
        for (int n = 0; n < 4; ++n) acc[m][n] = zz;

#define GSTAGE(colb, buf) do {                                                \
        const int _c = (colb); const int _o = (buf) * 8192;                   \
        GLDS16(srcQ + _c,         QsW + _o);                                  \
        GLDS16(srcQ + 53248 + _c, QsW + _o + 4096);                           \
        GLDS16(srcA + _c,         AsW + _o);                                  \
        GLDS16(srcA + 53248 + _c, AsW + _o + 4096);                           \
    } while (0)

    int cur = 0;
    GSTAGE(0, 0);
    __syncthreads();

    for (int ks = 0; ks < 13; ++ks) {
        const int nxt = cur ^ 1;
        if (ks < 12) GSTAGE((ks + 1) * 64, nxt);

        short8 qa[4], aa_[4];
        const char* Qc = Qs + cur * 8192;
        const char* Ac = Asl + cur * 8192;
#pragma unroll
        for (int m = 0; m < 4; ++m)
            qa[m] = *(const short8*)(Qc + (wr * 64 + m * 16 + fm) * 64 + chunkOff);
#pragma unroll
        for (int n = 0; n < 4; ++n)
            aa_[n] = *(const short8*)(Ac + (wc * 64 + n * 16 + fm) * 64 + chunkOff);
        __builtin_amdgcn_s_setprio(1);
#pragma unroll
        for (int m = 0; m < 4; ++m)
#pragma unroll
            for (int n = 0; n < 4; ++n)
                acc[m][n] = __builtin_amdgcn_mfma_f32_16x16x32_bf16(
                    qa[m], aa_[n], acc[m][n], 0, 0, 0);
        __builtin_amdgcn_s_setprio(0);
        __syncthreads();
        cur = nxt;
    }
#undef GSTAGE

#pragma unroll
    for (int m = 0; m < 4; ++m)
#pragma unroll
        for (int r = 0; r < 4; ++r) {
            float v = fmaxf(fmaxf(acc[m][0][r], acc[m][1][r]),
                            fmaxf(acc[m][2][r], acc[m][3][r]));
            v = fmaxf(v, __shfl_xor(v, 1));
            v = fmaxf(v, __shfl_xor(v, 2));
            v = fmaxf(v, __shfl_xor(v, 4));
            v = fmaxf(v, __shfl_xor(v, 8));
            if (fm == 0) rowM2[wr * 64 + m * 16 + (lane >> 4) * 4 + r][wc] = v;
        }
#pragma unroll
    for (int n = 0; n < 4; ++n) {
        float v = -1e30f;
#pragma unroll
        for (int m = 0; m < 4; ++m)
#pragma unroll
            for (int r = 0; r < 4; ++r) v = fmaxf(v, acc[m][n][r]);
        v = fmaxf(v, __shfl_xor(v, 16));
        v = fmaxf(v, __shfl_xor(v, 32));
        if (lane < 16) colM2[wc * 64 + n * 16 + lane][wr] = v;
    }
    __syncthreads();
    if (t < 128) {
        rowPart[((size_t)b * 4 + c) * 128 + t] = fmaxf(rowM2[t][0], rowM2[t][1]);
        colMg[(size_t)b * 512 + c * 128 + t]   = fmaxf(colM2[t][0], colM2[t][1]);
    }
}

// ---------------------------------------------------------------------------
// fused_pool: per-batch softmax over tanh(maxes) + pooling + cosine.
// ---------------------------------------------------------------------------
static __device__ __forceinline__ float block_reduce_max(float v, volatile float* red) {
    int t = threadIdx.x;
    red[t] = v; __syncthreads();
    for (int s = 128; s > 0; s >>= 1) {
        if (t < s) red[t] = fmaxf(red[t], red[t + s]);
        __syncthreads();
    }
    float r = red[0]; __syncthreads();
    return r;
}
static __device__ __forceinline__ float block_reduce_sum(float v, volatile float* red) {
    int t = threadIdx.x;
    red[t] = v; __syncthreads();
    for (int s = 128; s > 0; s >>= 1) {
        if (t < s) red[t] = red[t] + red[t + s];
        __syncthreads();
    }
    float r = red[0]; __syncthreads();
    return r;
}

__global__ __launch_bounds__(256) void fused_pool(
        const ushort16* __restrict__ Qv,   // [nb][128][416]
        const ushort16* __restrict__ Av,   // [nb][512][416]
        const float* __restrict__ rowPart, // [nb][4][128]
        const float* __restrict__ colMg,   // [nb][512]
        float* __restrict__ out)
{
    __shared__ float colv[ALn];
    __shared__ float roq[QLn];
    __shared__ float red[256];
    const int t = threadIdx.x, b = blockIdx.x;

    float v = -1e30f;
    if (t < QLn) {
        const float* rp = rowPart + (size_t)b * 512;
        float rm = fmaxf(fmaxf(rp[t], rp[128 + t]), fmaxf(rp[256 + t], rp[384 + t]));
        v = tanhf(rm);
    }
    float vmax = block_reduce_max(v, red);
    float ex = (t < QLn) ? __expf(v - vmax) : 0.f;
    float ssum = block_reduce_sum(ex, red);
    if (t < QLn) roq[t] = ex / ssum;

    float c0 = tanhf(colMg[(size_t)b * 512 + t]);
    float c1 = tanhf(colMg[(size_t)b * 512 + 256 + t]);
    float cmax = block_reduce_max(fmaxf(c0, c1), red);
    float e0 = __expf(c0 - cmax), e1 = __expf(c1 - cmax);
    float csum = block_reduce_sum(e0 + e1, red);
    colv[t] = e0 / csum;
    colv[t + 256] = e1 / csum;
    __syncthreads();

    float rq0 = 0.f, rq1 = 0.f, ra0 = 0.f, ra1 = 0.f;
    if (t < 208) {
        const uint32* Qb32 = (const uint32*)((const char*)Qv + (size_t)b * 106496);
#pragma unroll 4
        for (int q = 0; q < QLn; ++q) {
            float wv = roq[q];
            uint32 u = Qb32[q * 208 + t];
            rq0 = fmaf(bf_lo(u), wv, rq0);
            rq1 = fmaf(bf_hi(u), wv, rq1);
        }
        const uint32* Ab32 = (const uint32*)((const char*)Av + (size_t)b * 425984);
#pragma unroll 4
        for (int a = 0; a < ALn; ++a) {
            float wv = colv[a];
            uint32 u = Ab32[a * 208 + t];
            ra0 = fmaf(bf_lo(u), wv, ra0);
            ra1 = fmaf(bf_hi(u), wv, ra1);
        }
    }

    float dd  = block_reduce_sum(rq0 * ra0 + rq1 * ra1, red);
    float qq  = block_reduce_sum(rq0 * rq0 + rq1 * rq1, red);
    float aam = block_reduce_sum(ra0 * ra0 + ra1 * ra1, red);
    if (t == 0) {
        float nq = fmaxf(sqrtf(qq), 1e-8f);
        float na = fmaxf(sqrtf(aam), 1e-8f);
        out[b] = dd / (nq * na);
    }
}

// ---------------------------------------------------------------------------
// launch — ws_size-adaptive balanced batch chunking (pure function of ws_size)
// ws: [Wt2 | Wp2 | bias2 | bp2 | embbf | per-chunk: qb qpb ab rowP colM]
// ---------------------------------------------------------------------------
extern "C" void kernel_launch(void* const* d_in, const int* in_sizes, int n_in,
                              void* d_out, int out_size, void* d_ws, size_t ws_size,
                              hipStream_t stream)
{
    const int*   question = (const int*)d_in[0];
    const int*   answer   = (const int*)d_in[1];
    const float* emb      = (const float*)d_in[2];
    const float* conv_w   = (const float*)d_in[3];
    const float* conv_b   = (const float*)d_in[4];
    const float* U        = (const float*)d_in[5];
    float* out = (float*)d_out;
    char* ws = (char*)d_ws;

    const size_t WT2B   = (size_t)512 * 960 * 2;         // 983,040
    const size_t EMBB   = (size_t)NV * 640;              // 32,000,640
    const size_t FIXED0 = 2 * WT2B + 4096;               // 1,970,176
    const size_t FIXED  = FIXED0 + EMBB;                 // 33,970,816
    const size_t QB     = (size_t)QLn * OW * 2;          // 106,496
    const size_t AB     = (size_t)ALn * OW * 2;          // 425,984
    const size_t MXB    = 4096;
    const size_t PER_B  = 2 * QB + AB + MXB;             // 643,072

    size_t avail = (ws_size > FIXED) ? (ws_size - FIXED) : 0;
    int CB = (int)(avail / PER_B);
    if (CB > Bb) CB = Bb;
    if (CB < 1)  CB = 1;
    int nch = (Bb + CB - 1) / CB;
    int CBe = (Bb + nch - 1) / nch;      // balanced chunk size (<= CB)

    char*  wt2   = ws;
    char*  wp2   = ws + WT2B;
    float* bias2 = (float*)(ws + 2 * WT2B);
    float* bp2   = (float*)(ws + 2 * WT2B + 2048);
    char*  embbf = ws + FIXED0;
    char*  qb    = ws + FIXED;
    char*  qpb   = qb  + (size_t)CB * QB;
    char*  ab    = qpb + (size_t)CB * QB;
    float* rowP  = (float*)(ab + (size_t)CB * AB);
    float* colM  = rowP + (size_t)CB * 512;

    embcvt_kernel<<<NV, 128, 0, stream>>>(emb, embbf);
    prep_wt<<<512, 256, 0, stream>>>(conv_w, conv_b, (ushort16*)wt2, bias2);
    prep_wp<<<dim3(30, 4), 256, 0, stream>>>(conv_w, U, (ushort16*)wp2);
    prep_bp<<<1, 256, 0, stream>>>(conv_b, U, bp2);

    for (int b0 = 0; b0 < Bb; b0 += CBe) {
        int nb = (Bb - b0 < CBe) ? (Bb - b0) : CBe;
        int blocksA = ((nb * 4 + 7) / 8) * 8 * 3;
        int blocksQ = ((nb + 7) / 8) * 8 * 6;
        conv_all<<<blocksA + blocksQ, 256, 0, stream>>>(
            question + (size_t)b0 * QLn, answer + (size_t)b0 * ALn, embbf,
            wt2, wp2, bias2, bp2,
            (ushort16*)qb, (ushort16*)qpb, (ushort16*)ab, nb, blocksA);

        int blocksG = ((nb + 7) / 8) * 8 * 4;
        fused_g<<<blocksG, 256, 0, stream>>>((const ushort16*)qpb, (const ushort16*)ab,
                                             rowP, colM, nb);
        fused_pool<<<nb, 256, 0, stream>>>((const ushort16*)qb, (const ushort16*)ab,
                                           rowP, colM, out + b0);
    }
}